// Round 8
// baseline (440.230 us; speedup 1.0000x reference)
//
#include <hip/hip_runtime.h>
#include <math.h>

#define B_ROWS 1024
#define D_EMB  1568
#define H_HEADS 16
#define HSZ    98
#define FF_DIM 6272
#define OUT_DIM 784

typedef unsigned short ushort_t;
typedef __attribute__((ext_vector_type(8))) short short8;
typedef __attribute__((ext_vector_type(4))) float floatx4;

static __device__ __forceinline__ ushort_t f2bf(float f) {
    unsigned int u = __builtin_bit_cast(unsigned int, f);
    u = (u + 0x7fffu + ((u >> 16) & 1u)) >> 16;   // RNE; our values are never NaN
    return (ushort_t)u;
}
static __device__ __forceinline__ float bf2f(ushort_t h) {
    unsigned int u = ((unsigned int)h) << 16;
    return __builtin_bit_cast(float, u);
}

// ---------------- LayerNorm: fp32 in -> bf16 out ----------------
__global__ __launch_bounds__(256) void ln_kernel(const float* __restrict__ x,
                                                 const float* __restrict__ g,
                                                 const float* __restrict__ b,
                                                 ushort_t* __restrict__ out, int D) {
    const int row = blockIdx.x;
    const float* xr = x + (size_t)row * D;
    ushort_t* orow = out + (size_t)row * D;

    float s = 0.f, s2 = 0.f;
    for (int i = threadIdx.x; i < D; i += blockDim.x) {
        float v = xr[i];
        s += v; s2 += v * v;
    }
    #pragma unroll
    for (int off = 32; off > 0; off >>= 1) {
        s  += __shfl_down(s,  off, 64);
        s2 += __shfl_down(s2, off, 64);
    }
    __shared__ float ws_[8], ws2_[8];
    const int wave = threadIdx.x >> 6, lane = threadIdx.x & 63;
    if (lane == 0) { ws_[wave] = s; ws2_[wave] = s2; }
    __syncthreads();
    if (threadIdx.x == 0) {
        float ts = 0.f, ts2 = 0.f;
        for (int i = 0; i < 4; i++) { ts += ws_[i]; ts2 += ws2_[i]; }
        ws_[0] = ts; ws2_[0] = ts2;
    }
    __syncthreads();
    const float mean = ws_[0] / (float)D;
    const float var  = ws2_[0] / (float)D - mean * mean;
    const float inv  = rsqrtf(var + 1e-5f);
    for (int i = threadIdx.x; i < D; i += blockDim.x)
        orow[i] = f2bf((xr[i] - mean) * inv * g[i] + b[i]);
}

// ---------------- 64x64 transpose tile worker ----------------
// src fp32 [Kvalid][srcN]. dst bf16 row (dbase+n) col k, row-stride dstride.
// Rows n in [Nvalid, Npad) zero-filled. Kvalid % 4 == 0.
static __device__ __forceinline__ void transpose_tile(const float* __restrict__ src,
                                                      ushort_t* __restrict__ dst,
                                                      int srcN, int Kvalid,
                                                      int k0, int n0,
                                                      int Nvalid, int Npad,
                                                      int dstride, int dbase) {
    __shared__ float t[64][65];
    const int tid = threadIdx.x;
    const int tx = tid & 63, ty = tid >> 6;
    #pragma unroll
    for (int r = 0; r < 16; r++) {
        const int kl = ty + r * 4;
        const int k = k0 + kl, n = n0 + tx;
        t[tx][kl] = (k < Kvalid && n < Nvalid) ? src[(size_t)k * srcN + n] : 0.f;
    }
    __syncthreads();
    #pragma unroll
    for (int w = 0; w < 4; w++) {
        const int nl = (tid >> 4) + w * 16;
        const int kc = (tid & 15) * 4;
        const int n = n0 + nl, k = k0 + kc;
        if (n < Npad && k < Kvalid) {
            ushort4 uv;
            uv.x = f2bf(t[nl][kc + 0]);
            uv.y = f2bf(t[nl][kc + 1]);
            uv.z = f2bf(t[nl][kc + 2]);
            uv.w = f2bf(t[nl][kc + 3]);
            *(ushort4*)(dst + (size_t)(dbase + n) * dstride + k) = uv;
        }
    }
}

// prep1: Wq/Wk/Wv (H,1568,98) -> qkvt [4736][1568]; Wo (1568,1568) -> Wot [1664][1568].
__global__ __launch_bounds__(256) void prep1_kernel(const float* __restrict__ Wq,
                                                    const float* __restrict__ Wk,
                                                    const float* __restrict__ Wv,
                                                    const float* __restrict__ Wo,
                                                    ushort_t* __restrict__ qkvt,
                                                    ushort_t* __restrict__ Wot) {
    const int id = blockIdx.x;
    if (id < 2400) {
        const int ktile = id % 25;
        const int rest  = id / 25;
        const int ntile = rest & 1;
        const int hw    = rest >> 1;
        const int head  = hw & 15;
        const int which = hw >> 4;
        const float* src = (which == 0) ? Wq : (which == 1) ? Wk : Wv;
        src += (size_t)head * D_EMB * HSZ;
        transpose_tile(src, qkvt, HSZ, D_EMB, ktile * 64, ntile * 64,
                       HSZ, HSZ, D_EMB, which * D_EMB + head * HSZ);
    } else {
        const int id2 = id - 2400;
        const int ktile = id2 % 25;
        const int ntile = id2 / 25;
        transpose_tile(Wo, Wot, D_EMB, D_EMB, ktile * 64, ntile * 64,
                       D_EMB, 1664, D_EMB, 0);
    }
}

// generic single-weight transpose: fp32 [K][N] -> bf16 [Npad][K]
__global__ __launch_bounds__(256) void transpose_plain(const float* __restrict__ src,
                                                       ushort_t* __restrict__ dst,
                                                       int K, int N, int Npad) {
    transpose_tile(src, dst, N, K, blockIdx.y * 64, blockIdx.x * 64, N, Npad, K, 0);
}

// -------- barrier-free direct-MFMA GEMM (no LDS in K-loop) --------
// A: bf16 [1024][K] row-major.  Bt: bf16 [Npad][K] k-major.
// Block = 4 waves, each wave owns an independent 64x64 C-tile (2x2 wave grid over
// 128x128). Fragments loaded straight from global: lane (quad,l16) reads 16B at
// row (base + i*16 + l16), cols k+quad*8 — quads of one row cover a full 64B line,
// so the wave's 64 addresses form 16 fully-used cache lines. No __syncthreads in
// the K-loop -> no vmcnt(0) drain; waves pipeline independently.
// EPI 0: split-K bf16 plane P[z][1024][N].  EPI 1: bias + exact GELU -> bf16 (Z=1).
template <int EPI>
__global__ __launch_bounds__(256) void gemm_direct(const ushort_t* __restrict__ A,
                                                   const ushort_t* __restrict__ Bt,
                                                   ushort_t* __restrict__ P,
                                                   const float* __restrict__ bias,
                                                   int N, int K, int nkTot) {
    const int tid  = threadIdx.x;
    const int wave = tid >> 6, lane = tid & 63;
    const int quad = lane >> 4, l16 = lane & 15;
    const int wm = wave & 1, wn = wave >> 1;
    const int m0 = blockIdx.x * 128 + wm * 64;
    const int n0 = blockIdx.y * 128 + wn * 64;
    const int z = blockIdx.z, Z = gridDim.z;
    const int it0 = (int)((long long)nkTot * z / Z);
    const int it1 = (int)((long long)nkTot * (z + 1) / Z);

    const ushort_t* arow[4];
    const ushort_t* brow[4];
    #pragma unroll
    for (int i = 0; i < 4; i++)
        arow[i] = A + (size_t)(m0 + i * 16 + l16) * K + quad * 8;
    #pragma unroll
    for (int j = 0; j < 4; j++)
        brow[j] = Bt + (size_t)(n0 + j * 16 + l16) * K + quad * 8;

    floatx4 acc[4][4] = {};

    #pragma unroll 2
    for (int it = it0; it < it1; ++it) {
        const int k = it << 5;
        short8 af[4], bfr[4];
        #pragma unroll
        for (int i = 0; i < 4; i++) af[i]  = *(const short8*)(arow[i] + k);
        #pragma unroll
        for (int j = 0; j < 4; j++) bfr[j] = *(const short8*)(brow[j] + k);
        #pragma unroll
        for (int i = 0; i < 4; i++)
            #pragma unroll
            for (int j = 0; j < 4; j++)
                acc[i][j] = __builtin_amdgcn_mfma_f32_16x16x32_bf16(af[i], bfr[j], acc[i][j], 0, 0, 0);
    }

    ushort_t* Pz = (EPI == 0) ? (P + (size_t)z * B_ROWS * N) : P;
    #pragma unroll
    for (int i = 0; i < 4; i++) {
        const int rbase = m0 + i * 16 + quad * 4;
        #pragma unroll
        for (int j = 0; j < 4; j++) {
            const int col = n0 + j * 16 + l16;
            if (col < N) {
                #pragma unroll
                for (int r = 0; r < 4; r++) {
                    float v = acc[i][j][r];
                    if (EPI == 1) {
                        v += bias[col];
                        v = 0.5f * v * (1.f + erff(v * 0.70710678118654752f));
                    }
                    Pz[(size_t)(rbase + r) * N + col] = f2bf(v);
                }
            }
        }
    }
}

// -------- fused: Z-plane combine + bias + LayerNorm -> bf16 --------
template <int Z>
__global__ __launch_bounds__(256) void combine_ln_kernel(const ushort_t* __restrict__ P,
                                                         const float* __restrict__ bias,
                                                         const float* __restrict__ g,
                                                         const float* __restrict__ b,
                                                         ushort_t* __restrict__ out, int N) {
    __shared__ float t[D_EMB];
    __shared__ float ws_[8], ws2_[8];
    const int row = blockIdx.x;
    const size_t plane = (size_t)B_ROWS * N;
    const ushort_t* Pr = P + (size_t)row * N;
    const int half = N >> 1;

    float s = 0.f, s2 = 0.f;
    for (int i = threadIdx.x; i < half; i += blockDim.x) {
        float v0 = bias[2 * i], v1 = bias[2 * i + 1];
        #pragma unroll
        for (int zz = 0; zz < Z; zz++) {
            const ushort2 u = *(const ushort2*)(Pr + (size_t)zz * plane + 2 * i);
            v0 += bf2f(u.x); v1 += bf2f(u.y);
        }
        t[2 * i] = v0; t[2 * i + 1] = v1;
        s += v0 + v1; s2 += v0 * v0 + v1 * v1;
    }
    #pragma unroll
    for (int off = 32; off > 0; off >>= 1) {
        s  += __shfl_down(s,  off, 64);
        s2 += __shfl_down(s2, off, 64);
    }
    const int wave = threadIdx.x >> 6, lane = threadIdx.x & 63;
    if (lane == 0) { ws_[wave] = s; ws2_[wave] = s2; }
    __syncthreads();
    if (threadIdx.x == 0) {
        float ts = 0.f, ts2 = 0.f;
        for (int i = 0; i < 4; i++) { ts += ws_[i]; ts2 += ws2_[i]; }
        ws_[0] = ts; ws2_[0] = ts2;
    }
    __syncthreads();
    const float mean = ws_[0] / (float)N;
    const float var  = ws2_[0] / (float)N - mean * mean;
    const float inv  = rsqrtf(var + 1e-5f);
    ushort_t* orow = out + (size_t)row * N;
    for (int i = threadIdx.x; i < N; i += blockDim.x)
        orow[i] = f2bf((t[i] - mean) * inv * g[i] + b[i]);
}

// -------- combine Z planes + bias -> fp32 out --------
template <int Z>
__global__ __launch_bounds__(256) void combine_out_kernel(const ushort_t* __restrict__ P,
                                                          const float* __restrict__ bias,
                                                          float* __restrict__ out, int N) {
    const int c2 = blockIdx.x * 256 + threadIdx.x;
    if (c2 >= (N >> 1)) return;
    const int row = blockIdx.y;
    const size_t plane = (size_t)B_ROWS * N;
    const size_t off = (size_t)row * N + 2 * c2;
    float v0 = bias[2 * c2], v1 = bias[2 * c2 + 1];
    #pragma unroll
    for (int zz = 0; zz < Z; zz++) {
        const ushort2 u = *(const ushort2*)(P + (size_t)zz * plane + off);
        v0 += bf2f(u.x); v1 += bf2f(u.y);
    }
    out[off] = v0; out[off + 1] = v1;
}

// ---------------- rank-1 pseudo-attention (sums the 2 QKV partial planes inline) ----------------
__global__ __launch_bounds__(128) void attn_kernel(const ushort_t* __restrict__ P,
                                                   ushort_t* __restrict__ out) {
    const int bh = blockIdx.x;
    const int b = bh >> 4, h = bh & 15;
    const size_t base = (size_t)b * 4704 + h * HSZ;
    const size_t plane = (size_t)B_ROWS * 4704;

    __shared__ float ks[HSZ], vs[HSZ];
    __shared__ float kmax_s, kmin_s;

    const int t = threadIdx.x;
    if (t < HSZ) {
        ks[t] = bf2f(P[base + 1568 + t]) + bf2f(P[plane + base + 1568 + t]);
        vs[t] = bf2f(P[base + 3136 + t]) + bf2f(P[plane + base + 3136 + t]);
    }
    __syncthreads();
    if (t == 0) {
        float mx = -1e30f, mn = 1e30f;
        for (int j = 0; j < HSZ; j++) { mx = fmaxf(mx, ks[j]); mn = fminf(mn, ks[j]); }
        kmax_s = mx; kmin_s = mn;
    }
    __syncthreads();
    if (t < HSZ) {
        const float q = bf2f(P[base + t]) + bf2f(P[plane + base + t]);
        const float ti = q * 0.025253813613805268f;  // 1568^-0.5
        const float m = (ti >= 0.f) ? ti * kmax_s : ti * kmin_s;
        float s = 0.f, acc = 0.f;
        for (int j = 0; j < HSZ; j++) {
            const float e = __expf(ti * ks[j] - m);
            s += e; acc += e * vs[j];
        }
        out[(size_t)b * D_EMB + h * HSZ + t] = f2bf(acc / s);
    }
}

// ---------------- launch ----------------
// Workspace map (peak exactly 51,380,224 B = proven-safe). Serial liveness:
//   A [0, 20,070,400):  qkvt [0,14,852,096) + Wot [14,852,096,20,070,400)
//                       -> W1t [0,19,668,992) after combine_ln
//                       -> W2t [0,11,239,424) after W1 GEMM
//   P [20,070,400, 48,168,960): P_qkv Z=2 (19.27MB) -> P_Wo Z=4 (12.85MB)
//                       -> ff1 [20,070,400,32,915,456) + Pw2 Z=9 [32,915,456,47,366,144)
//   C [48,168,960, 51,380,224): h_bf [1024][1568] bf16 (LN1 -> attn -> LN2, serial)
extern "C" void kernel_launch(void* const* d_in, const int* in_sizes, int n_in,
                              void* d_out, int out_size, void* d_ws, size_t ws_size,
                              hipStream_t stream) {
    const float* x   = (const float*)d_in[0];
    const float* Wq  = (const float*)d_in[1];
    const float* Wk  = (const float*)d_in[2];
    const float* Wv  = (const float*)d_in[3];
    const float* Wo  = (const float*)d_in[4];
    const float* bo  = (const float*)d_in[5];
    const float* g1  = (const float*)d_in[6];
    const float* b1  = (const float*)d_in[7];
    const float* g2  = (const float*)d_in[8];
    const float* b2  = (const float*)d_in[9];
    const float* W1  = (const float*)d_in[10];
    const float* b1f = (const float*)d_in[11];
    const float* W2  = (const float*)d_in[12];
    const float* b2f = (const float*)d_in[13];
    float* out = (float*)d_out;

    char* w = (char*)d_ws;
    ushort_t* qkvt = (ushort_t*)(w);
    ushort_t* Wot  = (ushort_t*)(w + 14852096);
    ushort_t* W1t  = (ushort_t*)(w);
    ushort_t* W2t  = (ushort_t*)(w);
    ushort_t* Pb   = (ushort_t*)(w + 20070400);     // P_qkv / P_Wo planes
    ushort_t* ff1  = (ushort_t*)(w + 20070400);     // W1 output (planes dead)
    ushort_t* Pw2  = (ushort_t*)(w + 32915456);     // W2 partials Z=9
    ushort_t* h_bf = (ushort_t*)(w + 48168960);     // serial LN1/attn/LN2 buffer

    // 1. LN1 -> h_bf
    ln_kernel<<<B_ROWS, 256, 0, stream>>>(x, g1, b1, h_bf, D_EMB);

    // 2. prep1: Wqkv^T + Wo^T (3050 tiles)
    prep1_kernel<<<3050, 256, 0, stream>>>(Wq, Wk, Wv, Wo, qkvt, Wot);

    // 3. QKV GEMM: N=4704, K=1568, Z=2, grid 8x37x2 = 592 blocks
    gemm_direct<0><<<dim3(8, 37, 2), 256, 0, stream>>>(h_bf, qkvt, Pb, nullptr, 4704, D_EMB, 49);

    // 4. attention (sums 2 planes) -> h_bf
    attn_kernel<<<B_ROWS * H_HEADS, 128, 0, stream>>>(Pb, h_bf);

    // 5. Wo GEMM: N=1568, Z=4, grid 8x13x4 = 416 blocks
    gemm_direct<0><<<dim3(8, 13, 4), 256, 0, stream>>>(h_bf, Wot, Pb, nullptr, D_EMB, D_EMB, 49);

    // 6. combine+bias+LN2 -> h_bf
    combine_ln_kernel<4><<<B_ROWS, 256, 0, stream>>>(Pb, bo, g2, b2, h_bf, D_EMB);

    // 7. W1^T [6272][1568] (region A free)
    transpose_plain<<<dim3(98, 25), 256, 0, stream>>>(W1, W1t, D_EMB, FF_DIM, FF_DIM);

    // 8. W1 GEMM: N=6272, Z=1, fused bias+GELU -> ff1, grid 8x49 = 392 blocks
    gemm_direct<1><<<dim3(8, 49, 1), 256, 0, stream>>>(h_bf, W1t, ff1, b1f, FF_DIM, D_EMB, 49);

    // 9. W2^T [896][6272] (W1t dead)
    transpose_plain<<<dim3(14, 98), 256, 0, stream>>>(W2, W2t, FF_DIM, OUT_DIM, 896);

    // 10. W2 GEMM: N=784, K=6272, Z=9, grid 8x7x9 = 504 blocks
    gemm_direct<0><<<dim3(8, 7, 9), 256, 0, stream>>>(ff1, W2t, Pw2, nullptr, OUT_DIM, FF_DIM, 196);

    // 11. combine Z=9 + bias -> out (fp32)
    combine_out_kernel<9><<<dim3(2, B_ROWS), 256, 0, stream>>>(Pw2, b2f, out, OUT_DIM);
}

// Round 9
// 329.768 us; speedup vs baseline: 1.3350x; 1.3350x over previous
//
#include <hip/hip_runtime.h>
#include <math.h>

#define B_ROWS 1024
#define D_EMB  1568
#define KP     1600      // D_EMB padded to BK=64 multiple
#define H_HEADS 16
#define HSZ    98
#define FF_DIM 6272
#define OUT_DIM 784

typedef unsigned short ushort_t;
typedef __attribute__((ext_vector_type(8))) short short8;
typedef __attribute__((ext_vector_type(4))) float floatx4;

static __device__ __forceinline__ ushort_t f2bf(float f) {
    unsigned int u = __builtin_bit_cast(unsigned int, f);
    u = (u + 0x7fffu + ((u >> 16) & 1u)) >> 16;   // RNE; values never NaN
    return (ushort_t)u;
}
static __device__ __forceinline__ float bf2f(ushort_t h) {
    unsigned int u = ((unsigned int)h) << 16;
    return __builtin_bit_cast(float, u);
}

// async 16B global -> LDS (wave-uniform base; HW scatters lane*16)
static __device__ __forceinline__ void load16_to_lds(const void* g, void* l) {
    __builtin_amdgcn_global_load_lds(
        (const __attribute__((address_space(1))) void*)g,
        (__attribute__((address_space(3))) void*)l,
        16, 0, 0);
}

// ---------------- LN row worker (one block per row), pad cols zeroed ----------------
static __device__ void ln_row(const float* __restrict__ xr,
                              const float* __restrict__ g,
                              const float* __restrict__ b,
                              ushort_t* __restrict__ orow, int D, int DPAD) {
    __shared__ float ws_[8], ws2_[8];
    float s = 0.f, s2 = 0.f;
    for (int i = threadIdx.x; i < D; i += blockDim.x) {
        float v = xr[i];
        s += v; s2 += v * v;
    }
    #pragma unroll
    for (int off = 32; off > 0; off >>= 1) {
        s  += __shfl_down(s,  off, 64);
        s2 += __shfl_down(s2, off, 64);
    }
    const int wave = threadIdx.x >> 6, lane = threadIdx.x & 63;
    if (lane == 0) { ws_[wave] = s; ws2_[wave] = s2; }
    __syncthreads();
    if (threadIdx.x == 0) {
        float ts = 0.f, ts2 = 0.f;
        for (int i = 0; i < 4; i++) { ts += ws_[i]; ts2 += ws2_[i]; }
        ws_[0] = ts; ws2_[0] = ts2;
    }
    __syncthreads();
    const float mean = ws_[0] / (float)D;
    const float var  = ws2_[0] / (float)D - mean * mean;
    const float inv  = rsqrtf(var + 1e-5f);
    for (int i = threadIdx.x; i < DPAD; i += blockDim.x)
        orow[i] = (i < D) ? f2bf((xr[i] - mean) * inv * g[i] + b[i]) : (ushort_t)0;
}

// ---------------- 64x64 transpose tile worker ----------------
// src fp32 [Kvalid][srcN]. dst bf16 row (dbase+n) col k, row-stride dstride.
// Rows n in [Nvalid,Npad) zero-filled; k-pad cols (>=Kvalid) left untouched
// (finite poison; A-side zeros null the products).
static __device__ __forceinline__ void transpose_tile(const float* __restrict__ src,
                                                      ushort_t* __restrict__ dst,
                                                      int srcN, int Kvalid,
                                                      int k0, int n0,
                                                      int Nvalid, int Npad,
                                                      int dstride, int dbase) {
    __shared__ float t[64][65];
    const int tid = threadIdx.x;
    const int tx = tid & 63, ty = tid >> 6;
    #pragma unroll
    for (int r = 0; r < 16; r++) {
        const int kl = ty + r * 4;
        const int k = k0 + kl, n = n0 + tx;
        t[tx][kl] = (k < Kvalid && n < Nvalid) ? src[(size_t)k * srcN + n] : 0.f;
    }
    __syncthreads();
    #pragma unroll
    for (int w = 0; w < 4; w++) {
        const int nl = (tid >> 4) + w * 16;
        const int kc = (tid & 15) * 4;
        const int n = n0 + nl, k = k0 + kc;
        if (n < Npad && k < Kvalid) {
            ushort4 uv;
            uv.x = f2bf(t[nl][kc + 0]);
            uv.y = f2bf(t[nl][kc + 1]);
            uv.z = f2bf(t[nl][kc + 2]);
            uv.w = f2bf(t[nl][kc + 3]);
            *(ushort4*)(dst + (size_t)(dbase + n) * dstride + k) = uv;
        }
    }
}

// prep1x: ids 0..1023 LN1 rows; 1024..3423 qkv transpose tiles; 3424..4073 Wo tiles.
__global__ __launch_bounds__(256) void prep1x_kernel(const float* __restrict__ x,
                                                     const float* __restrict__ g1,
                                                     const float* __restrict__ b1,
                                                     const float* __restrict__ Wq,
                                                     const float* __restrict__ Wk,
                                                     const float* __restrict__ Wv,
                                                     const float* __restrict__ Wo,
                                                     ushort_t* __restrict__ h_bf,
                                                     ushort_t* __restrict__ qkvt,
                                                     ushort_t* __restrict__ Wot) {
    const int id = blockIdx.x;
    if (id < 1024) {
        ln_row(x + (size_t)id * D_EMB, g1, b1, h_bf + (size_t)id * KP, D_EMB, KP);
    } else if (id < 3424) {
        const int t = id - 1024;
        const int ktile = t % 25;
        const int rest  = t / 25;
        const int ntile = rest & 1;
        const int hw    = rest >> 1;
        const int head  = hw & 15;
        const int which = hw >> 4;
        const float* src = (which == 0) ? Wq : (which == 1) ? Wk : Wv;
        src += (size_t)head * D_EMB * HSZ;
        transpose_tile(src, qkvt, HSZ, D_EMB, ktile * 64, ntile * 64,
                       HSZ, HSZ, KP, which * D_EMB + head * HSZ);
    } else {
        const int t = id - 3424;
        const int ktile = t % 25;
        const int ntile = t / 25;
        transpose_tile(Wo, Wot, D_EMB, D_EMB, ktile * 64, ntile * 64,
                       D_EMB, 1664, KP, 0);
    }
}

// -------- bf16 MFMA GEMM, 128x128, BK=64, XCD-swizzled 1-D grid --------
// A: bf16 [1024][Kstride] (k-pad zeroed).  Bt: bf16 [Npad][Kstride] k-major.
// id = q<<6 | m<<3 | r;  nz = r + 8q (n,z index); all 8 m-blocks of one (n,z)
// share id%8 -> same XCD -> B-tile reused 8x out of that XCD's L2.
// EPI 0: split-K bf16 plane P[z][1024][N].  EPI 1: bias + exact GELU -> bf16 (Z=1).
template <int EPI>
__global__ __launch_bounds__(256) void gemm_lds(const ushort_t* __restrict__ A,
                                                const ushort_t* __restrict__ Bt,
                                                ushort_t* __restrict__ P,
                                                const float* __restrict__ bias,
                                                int N, int Kstride, int nkTot,
                                                int NT, int Z) {
    __shared__ __align__(16) ushort_t As[2 * 128 * 32];   // [ks][row][32]
    __shared__ __align__(16) ushort_t Bs[2 * 128 * 32];

    const int id = blockIdx.x;
    const int nz = (id & 7) + ((id >> 6) << 3);
    if (nz >= NT * Z) return;
    const int mq = (id >> 3) & 7;
    const int z  = nz / NT;
    const int nt = nz - z * NT;
    const int m0 = mq * 128;
    const int n0 = nt * 128;
    const int it0 = (int)((long long)nkTot * z / Z);
    const int it1 = (int)((long long)nkTot * (z + 1) / Z);

    const int tid  = threadIdx.x;
    const int wave = tid >> 6, lane = tid & 63;
    const int quad = lane >> 4, l16 = lane & 15;
    const int srow = lane >> 2;          // 0..15
    const int scol = (lane & 3) << 3;    // 0,8,16,24
    const int wm = wave & 1, wn = wave >> 1;

    floatx4 acc[4][4] = {};

    for (int it = it0; it < it1; ++it) {
        const int k0 = it << 6;
        #pragma unroll
        for (int c = 0; c < 2; ++c) {
            const int rg = wave * 2 + c;             // wave-uniform rowgroup
            const int row = rg * 16 + srow;
            #pragma unroll
            for (int ks = 0; ks < 2; ++ks) {
                load16_to_lds(A  + (size_t)(m0 + row) * Kstride + k0 + ks * 32 + scol,
                              &As[ks * 4096 + rg * 512]);
                load16_to_lds(Bt + (size_t)(n0 + row) * Kstride + k0 + ks * 32 + scol,
                              &Bs[ks * 4096 + rg * 512]);
            }
        }
        __syncthreads();

        #pragma unroll
        for (int ks = 0; ks < 2; ++ks) {
            short8 af[4], bfr[4];
            #pragma unroll
            for (int i = 0; i < 4; i++)
                af[i] = *(const short8*)&As[ks * 4096 + (wm * 64 + i * 16 + l16) * 32 + quad * 8];
            #pragma unroll
            for (int j = 0; j < 4; j++)
                bfr[j] = *(const short8*)&Bs[ks * 4096 + (wn * 64 + j * 16 + l16) * 32 + quad * 8];
            #pragma unroll
            for (int i = 0; i < 4; i++)
                #pragma unroll
                for (int j = 0; j < 4; j++)
                    acc[i][j] = __builtin_amdgcn_mfma_f32_16x16x32_bf16(af[i], bfr[j], acc[i][j], 0, 0, 0);
        }
        __syncthreads();
    }

    ushort_t* Pz = (EPI == 0) ? (P + (size_t)z * B_ROWS * N) : P;
    #pragma unroll
    for (int i = 0; i < 4; i++) {
        const int rbase = m0 + wm * 64 + i * 16 + quad * 4;
        #pragma unroll
        for (int j = 0; j < 4; j++) {
            const int col = n0 + wn * 64 + j * 16 + l16;
            if (col < N) {
                #pragma unroll
                for (int r = 0; r < 4; r++) {
                    float v = acc[i][j][r];
                    if (EPI == 1) {
                        v += bias[col];
                        v = 0.5f * v * (1.f + erff(v * 0.70710678118654752f));
                    }
                    Pz[(size_t)(rbase + r) * N + col] = f2bf(v);
                }
            }
        }
    }
}

// -------- combine Z planes + bias + LayerNorm row worker --------
template <int Z>
static __device__ void combine_ln_row(const ushort_t* __restrict__ P,
                                      const float* __restrict__ bias,
                                      const float* __restrict__ g,
                                      const float* __restrict__ b,
                                      ushort_t* __restrict__ out,
                                      int row, int N, int NPAD) {
    __shared__ float t[D_EMB];
    __shared__ float ws_[8], ws2_[8];
    const size_t plane = (size_t)B_ROWS * N;
    const ushort_t* Pr = P + (size_t)row * N;
    const int half = N >> 1;

    float s = 0.f, s2 = 0.f;
    for (int i = threadIdx.x; i < half; i += blockDim.x) {
        float v0 = bias[2 * i], v1 = bias[2 * i + 1];
        #pragma unroll
        for (int zz = 0; zz < Z; zz++) {
            const ushort2 u = *(const ushort2*)(Pr + (size_t)zz * plane + 2 * i);
            v0 += bf2f(u.x); v1 += bf2f(u.y);
        }
        t[2 * i] = v0; t[2 * i + 1] = v1;
        s += v0 + v1; s2 += v0 * v0 + v1 * v1;
    }
    #pragma unroll
    for (int off = 32; off > 0; off >>= 1) {
        s  += __shfl_down(s,  off, 64);
        s2 += __shfl_down(s2, off, 64);
    }
    const int wave = threadIdx.x >> 6, lane = threadIdx.x & 63;
    if (lane == 0) { ws_[wave] = s; ws2_[wave] = s2; }
    __syncthreads();
    if (threadIdx.x == 0) {
        float ts = 0.f, ts2 = 0.f;
        for (int i = 0; i < 4; i++) { ts += ws_[i]; ts2 += ws2_[i]; }
        ws_[0] = ts; ws2_[0] = ts2;
    }
    __syncthreads();
    const float mean = ws_[0] / (float)N;
    const float var  = ws2_[0] / (float)N - mean * mean;
    const float inv  = rsqrtf(var + 1e-5f);
    ushort_t* orow = out + (size_t)row * NPAD;
    for (int i = threadIdx.x; i < NPAD; i += blockDim.x)
        orow[i] = (i < N) ? f2bf((t[i] - mean) * inv * g[i] + b[i]) : (ushort_t)0;
}

// mid: ids 0..1023 combine_ln(Z=4)+LN2 rows; 1024..3473 W1^T tiles; 3474..4845 W2^T tiles.
__global__ __launch_bounds__(256) void mid_kernel(const ushort_t* __restrict__ P,
                                                  const float* __restrict__ bo,
                                                  const float* __restrict__ g2,
                                                  const float* __restrict__ b2,
                                                  ushort_t* __restrict__ h_bf,
                                                  const float* __restrict__ W1,
                                                  const float* __restrict__ W2,
                                                  ushort_t* __restrict__ W1t,
                                                  ushort_t* __restrict__ W2t) {
    const int id = blockIdx.x;
    if (id < 1024) {
        combine_ln_row<4>(P, bo, g2, b2, h_bf, id, D_EMB, KP);
    } else if (id < 3474) {
        const int t = id - 1024;
        const int ktile = t % 25;
        const int ntile = t / 25;
        transpose_tile(W1, W1t, FF_DIM, D_EMB, ktile * 64, ntile * 64,
                       FF_DIM, FF_DIM, KP, 0);
    } else {
        const int t = id - 3474;
        const int ktile = t % 98;
        const int ntile = t / 98;
        transpose_tile(W2, W2t, OUT_DIM, FF_DIM, ktile * 64, ntile * 64,
                       OUT_DIM, 896, FF_DIM, 0);
    }
}

// -------- combine Z planes + bias -> fp32 out --------
template <int Z>
__global__ __launch_bounds__(256) void combine_out_kernel(const ushort_t* __restrict__ P,
                                                          const float* __restrict__ bias,
                                                          float* __restrict__ out, int N) {
    const int c2 = blockIdx.x * 256 + threadIdx.x;
    if (c2 >= (N >> 1)) return;
    const int row = blockIdx.y;
    const size_t plane = (size_t)B_ROWS * N;
    const size_t off = (size_t)row * N + 2 * c2;
    float v0 = bias[2 * c2], v1 = bias[2 * c2 + 1];
    #pragma unroll
    for (int zz = 0; zz < Z; zz++) {
        const ushort2 u = *(const ushort2*)(P + (size_t)zz * plane + off);
        v0 += bf2f(u.x); v1 += bf2f(u.y);
    }
    out[off] = v0; out[off + 1] = v1;
}

// ---------------- rank-1 pseudo-attention (sums 2 QKV planes inline) ----------------
// P: 2 bf16 planes [1024][4704]: q at col h*98+e, k at +1568, v at +3136. out: [1024][KP].
__global__ __launch_bounds__(128) void attn_kernel(const ushort_t* __restrict__ P,
                                                   ushort_t* __restrict__ out) {
    const int bh = blockIdx.x;
    const int b = bh >> 4, h = bh & 15;
    const size_t base = (size_t)b * 4704 + h * HSZ;
    const size_t plane = (size_t)B_ROWS * 4704;

    __shared__ float ks[HSZ], vs[HSZ];
    __shared__ float kmax_s, kmin_s;

    const int t = threadIdx.x;
    if (t < HSZ) {
        ks[t] = bf2f(P[base + 1568 + t]) + bf2f(P[plane + base + 1568 + t]);
        vs[t] = bf2f(P[base + 3136 + t]) + bf2f(P[plane + base + 3136 + t]);
    }
    __syncthreads();
    if (t == 0) {
        float mx = -1e30f, mn = 1e30f;
        for (int j = 0; j < HSZ; j++) { mx = fmaxf(mx, ks[j]); mn = fminf(mn, ks[j]); }
        kmax_s = mx; kmin_s = mn;
    }
    __syncthreads();
    if (t < HSZ) {
        const float q = bf2f(P[base + t]) + bf2f(P[plane + base + t]);
        const float ti = q * 0.025253813613805268f;  // 1568^-0.5
        const float m = (ti >= 0.f) ? ti * kmax_s : ti * kmin_s;
        float s = 0.f, acc = 0.f;
        for (int j = 0; j < HSZ; j++) {
            const float e = __expf(ti * ks[j] - m);
            s += e; acc += e * vs[j];
        }
        out[(size_t)b * KP + h * HSZ + t] = f2bf(acc / s);
    }
}

// ---------------- launch ----------------
// Workspace map (peak exactly 51,380,224 B = proven-safe). Serial liveness:
//   A [0, 20,480,000):  qkvt [0,15,155,200) + Wot [15,155,200,20,480,000)
//                       -> W1t [0,20,070,400) after Wo GEMM (written by mid_kernel)
//                       -> Pw2 Z=9 [0,14,450,688) after W1 GEMM
//   P [20,480,000, 44,564,480): P_qkv Z=2 (19.27MB) -> P_Wo Z=4 (12.85MB)
//                       -> ff1 [20,480,000,33,325,056) + W2t [33,325,056,44,564,480)
//   C [48,103,424, 51,380,224): h_bf [1024][KP] bf16 (LN1 -> attn -> LN2, serial)
extern "C" void kernel_launch(void* const* d_in, const int* in_sizes, int n_in,
                              void* d_out, int out_size, void* d_ws, size_t ws_size,
                              hipStream_t stream) {
    const float* x   = (const float*)d_in[0];
    const float* Wq  = (const float*)d_in[1];
    const float* Wk  = (const float*)d_in[2];
    const float* Wv  = (const float*)d_in[3];
    const float* Wo  = (const float*)d_in[4];
    const float* bo  = (const float*)d_in[5];
    const float* g1  = (const float*)d_in[6];
    const float* b1  = (const float*)d_in[7];
    const float* g2  = (const float*)d_in[8];
    const float* b2  = (const float*)d_in[9];
    const float* W1  = (const float*)d_in[10];
    const float* b1f = (const float*)d_in[11];
    const float* W2  = (const float*)d_in[12];
    const float* b2f = (const float*)d_in[13];
    float* out = (float*)d_out;

    char* w = (char*)d_ws;
    ushort_t* qkvt = (ushort_t*)(w);
    ushort_t* Wot  = (ushort_t*)(w + 15155200);
    ushort_t* W1t  = (ushort_t*)(w);
    ushort_t* Pw2  = (ushort_t*)(w);                // W2 partials Z=9 (post-W1)
    ushort_t* Pb   = (ushort_t*)(w + 20480000);     // P_qkv / P_Wo planes
    ushort_t* ff1  = (ushort_t*)(w + 20480000);     // W1 output (planes dead)
    ushort_t* W2t  = (ushort_t*)(w + 33325056);
    ushort_t* h_bf = (ushort_t*)(w + 48103424);     // serial LN1/attn/LN2 buffer

    // 1. LN1 + Wqkv^T + Wo^T (one dispatch, 4074 blocks)
    prep1x_kernel<<<4074, 256, 0, stream>>>(x, g1, b1, Wq, Wk, Wv, Wo, h_bf, qkvt, Wot);

    // 2. QKV GEMM: N=4704, NT=37, Z=2 -> 592 blocks (grid 640, swizzled)
    gemm_lds<0><<<640, 256, 0, stream>>>(h_bf, qkvt, Pb, nullptr, 4704, KP, 25, 37, 2);

    // 3. attention (sums 2 planes) -> h_bf
    attn_kernel<<<B_ROWS * H_HEADS, 128, 0, stream>>>(Pb, h_bf);

    // 4. Wo GEMM: N=1568, NT=13, Z=4 -> 416 blocks (grid 448)
    gemm_lds<0><<<448, 256, 0, stream>>>(h_bf, Wot, Pb, nullptr, D_EMB, KP, 25, 13, 4);

    // 5. combine+bias+LN2 + W1^T + W2^T (one dispatch, 4846 blocks)
    mid_kernel<<<4846, 256, 0, stream>>>(Pb, bo, g2, b2, h_bf, W1, W2, W1t, W2t);

    // 6. W1 GEMM: N=6272, NT=49, Z=1, fused bias+GELU -> ff1 (grid 448)
    gemm_lds<1><<<448, 256, 0, stream>>>(h_bf, W1t, ff1, b1f, FF_DIM, KP, 25, 49, 1);

    // 7. W2 GEMM: N=784, K=6272, NT=7, Z=9 -> 504 blocks (grid 512)
    gemm_lds<0><<<512, 256, 0, stream>>>(ff1, W2t, Pw2, nullptr, OUT_DIM, FF_DIM, 98, 7, 9);

    // 8. combine Z=9 + bias -> out (fp32)
    combine_out_kernel<9><<<dim3(2, B_ROWS), 256, 0, stream>>>(Pw2, b2f, out, OUT_DIM);
}